// Round 1
// baseline (1855.896 us; speedup 1.0000x reference)
//
#include <hip/hip_runtime.h>
#include <hip/hip_bf16.h>

// GENConv fused: out = softmax(adj) @ x @ W + b
//   = diag(1/rowsum(exp(adj))) * (exp(adj) @ (x@W)) + b     (adj in [0,1) -> no max needed)
// Kernel 1: yT[k][j] = bf16( (x @ W)[j][k] )   (transposed, bf16, in d_ws)
// Kernel 2: fused exp + GEMM (MFMA bf16) + rowsum + scale + bias

typedef short  short8  __attribute__((ext_vector_type(8)));
typedef short  short4v __attribute__((ext_vector_type(4)));
typedef float  floatx4 __attribute__((ext_vector_type(4)));

#define NN 16384
#define DD 128

__device__ __forceinline__ short f2bf(float f) {
    unsigned u = __float_as_uint(f);
    u += 0x7fff + ((u >> 16) & 1);      // RNE
    return (short)(u >> 16);
}

// ---------------- Kernel 1: yT = (x @ W)^T in bf16 ----------------
// grid 256, block 256. Block handles 64 j-rows. MFMA: A = W^T (staged LDS), B = x rows.
__global__ __launch_bounds__(256, 2) void xw_kernel(
    const float* __restrict__ x, const float* __restrict__ W, short* __restrict__ yT)
{
    __shared__ short WT[128 * 136];           // WT[k][d], padded row = 136 shorts
    const int t  = threadIdx.x;
    const int j0 = blockIdx.x * 64;

    // stage W^T as bf16 (transpose during store; one-time, conflicts acceptable)
    #pragma unroll
    for (int i = 0; i < 16; ++i) {
        int f4 = t + 256 * i;                 // 0..4095 float4s of W (128x128)
        int d = f4 >> 5, c4 = f4 & 31;
        float4 v = ((const float4*)W)[f4];
        WT[(4*c4 + 0) * 136 + d] = f2bf(v.x);
        WT[(4*c4 + 1) * 136 + d] = f2bf(v.y);
        WT[(4*c4 + 2) * 136 + d] = f2bf(v.z);
        WT[(4*c4 + 3) * 136 + d] = f2bf(v.w);
    }
    __syncthreads();

    const int lane = t & 63, w = t >> 6;
    const int nl = lane & 15, q = lane >> 4;
    const int j = j0 + 16 * w + nl;           // this lane's x row (B-operand n index)
    const float* xrow = x + (size_t)j * DD + 8 * q;

    floatx4 acc[8];
    #pragma unroll
    for (int kt = 0; kt < 8; ++kt) acc[kt] = (floatx4){0.f, 0.f, 0.f, 0.f};

    #pragma unroll
    for (int dstep = 0; dstep < 4; ++dstep) {
        float4 v0 = *(const float4*)(xrow + 32 * dstep);
        float4 v1 = *(const float4*)(xrow + 32 * dstep + 4);
        short8 bf;
        bf[0] = f2bf(v0.x); bf[1] = f2bf(v0.y); bf[2] = f2bf(v0.z); bf[3] = f2bf(v0.w);
        bf[4] = f2bf(v1.x); bf[5] = f2bf(v1.y); bf[6] = f2bf(v1.z); bf[7] = f2bf(v1.w);
        #pragma unroll
        for (int kt = 0; kt < 8; ++kt) {
            short8 af = *(const short8*)(&WT[(16*kt + nl) * 136 + 32*dstep + 8*q]);
            acc[kt] = __builtin_amdgcn_mfma_f32_16x16x32_bf16(af, bf, acc[kt], 0, 0, 0);
        }
    }
    // D layout: row(m=k) = 4q + r (+16kt), col(n=j) = nl  -> store transposed output yT[k][j]
    #pragma unroll
    for (int kt = 0; kt < 8; ++kt) {
        #pragma unroll
        for (int r = 0; r < 4; ++r)
            yT[(size_t)(16*kt + 4*q + r) * NN + j] = f2bf(acc[kt][r]);
    }
}

// ---------------- Kernel 2: fused exp-GEMM ----------------
// grid 256 (1 block/CU), block 256 (4 waves). Block: rows i0..i0+63, all 128 cols, K-loop BK=128.
__global__ __launch_bounds__(256, 1) void attn_kernel(
    const float* __restrict__ adj, const short* __restrict__ yT,
    const float* __restrict__ bias, float* __restrict__ out)
{
    __shared__ short A_lds[64 * 136];         // exp(adj) tile, bf16, row = 136 shorts
    __shared__ short B_lds[128 * 136];        // yT tile (n-major), bf16
    __shared__ float rs[64];                  // row sums

    const int t  = threadIdx.x;
    const int i0 = blockIdx.x * 64;

    // A staging coords: thread -> cols 4cg..4cg+3, rows rg+8p (p=0..7)
    const int cg = t & 31, rg = t >> 5;
    const float* aptr = adj + (size_t)(i0 + rg) * NN + 4 * cg;
    // B staging coords: thread -> yT row bn, k-half bh (64 bf16 = 4 x uint4)
    const int bn = t >> 1, bh = t & 1;
    const short* bptr = yT + (size_t)bn * NN + 64 * bh;

    float4 pa[8];
    uint4  pb[8];
    float  psum[8];
    floatx4 acc[8];
    #pragma unroll
    for (int p = 0; p < 8; ++p) psum[p] = 0.f;
    #pragma unroll
    for (int n = 0; n < 8; ++n) acc[n] = (floatx4){0.f, 0.f, 0.f, 0.f};

    const int lane = t & 63, w = t >> 6;
    const int m = lane & 15, q = lane >> 4;
    const short* Arow = &A_lds[(16*w + m) * 136];

    auto load_tile = [&](int kb) {
        #pragma unroll
        for (int p = 0; p < 8; ++p)
            pa[p] = *(const float4*)(aptr + (size_t)(8 * p) * NN + kb);
        #pragma unroll
        for (int jj = 0; jj < 8; ++jj)
            pb[jj] = *(const uint4*)(bptr + kb + 8 * jj);
    };
    auto store_tile = [&]() {
        #pragma unroll
        for (int p = 0; p < 8; ++p) {
            float e0 = __expf(pa[p].x), e1 = __expf(pa[p].y);
            float e2 = __expf(pa[p].z), e3 = __expf(pa[p].w);
            psum[p] += (e0 + e1) + (e2 + e3);
            short4v v; v[0] = f2bf(e0); v[1] = f2bf(e1); v[2] = f2bf(e2); v[3] = f2bf(e3);
            *(short4v*)&A_lds[(rg + 8*p) * 136 + 4*cg] = v;
        }
        #pragma unroll
        for (int jj = 0; jj < 8; ++jj)
            *(uint4*)&B_lds[bn * 136 + 64*bh + 8*jj] = pb[jj];
    };
    auto mma_tile = [&]() {
        #pragma unroll
        for (int ks = 0; ks < 4; ++ks) {
            short8 af = *(const short8*)(Arow + 32*ks + 8*q);
            #pragma unroll
            for (int nt = 0; nt < 8; ++nt) {
                short8 bf = *(const short8*)(&B_lds[(16*nt + m) * 136 + 32*ks + 8*q]);
                acc[nt] = __builtin_amdgcn_mfma_f32_16x16x32_bf16(af, bf, acc[nt], 0, 0, 0);
            }
        }
    };

    load_tile(0);
    store_tile();
    __syncthreads();
    for (int it = 1; it < NN / 128; ++it) {
        load_tile(it * 128);      // prefetch next tile into registers (stays in flight over MFMA)
        mma_tile();               // MFMA on tile it-1 (in LDS)
        __syncthreads();          // all waves done reading LDS
        store_tile();             // exp + convert + write tile it to LDS, accumulate rowsums
        __syncthreads();
    }
    mma_tile();                   // last tile

    // rowsum reduction: 32 lanes share each row set
    #pragma unroll
    for (int p = 0; p < 8; ++p) {
        float v = psum[p];
        v += __shfl_xor(v, 1);
        v += __shfl_xor(v, 2);
        v += __shfl_xor(v, 4);
        v += __shfl_xor(v, 8);
        v += __shfl_xor(v, 16);
        if (cg == 0) rs[rg + 8*p] = v;
    }
    __syncthreads();

    float inv[4];
    #pragma unroll
    for (int r = 0; r < 4; ++r) inv[r] = 1.0f / rs[16*w + 4*q + r];
    #pragma unroll
    for (int nt = 0; nt < 8; ++nt) {
        float bv = bias[16*nt + m];
        #pragma unroll
        for (int r = 0; r < 4; ++r)
            out[(size_t)(i0 + 16*w + 4*q + r) * DD + 16*nt + m] = acc[nt][r] * inv[r] + bv;
    }
}

extern "C" void kernel_launch(void* const* d_in, const int* in_sizes, int n_in,
                              void* d_out, int out_size, void* d_ws, size_t ws_size,
                              hipStream_t stream)
{
    const float* x    = (const float*)d_in[0];
    const float* adj  = (const float*)d_in[1];
    const float* W    = (const float*)d_in[2];
    const float* bias = (const float*)d_in[3];
    float* out = (float*)d_out;
    short* yT  = (short*)d_ws;                 // 128 x 16384 bf16 = 4 MiB

    hipLaunchKernelGGL(xw_kernel,   dim3(256), dim3(256), 0, stream, x, W, yT);
    hipLaunchKernelGGL(attn_kernel, dim3(256), dim3(256), 0, stream, adj, yT, bias, out);
}

// Round 2
// 1762.761 us; speedup vs baseline: 1.0528x; 1.0528x over previous
//
#include <hip/hip_runtime.h>
#include <hip/hip_bf16.h>

// GENConv fused: out = softmax(adj) @ x @ W + b
//   = diag(1/rowsum(exp(adj))) * (exp(adj) @ (x@W)) + b     (adj in [0,1) -> no max needed)
// Kernel 1: yT[k][j] = bf16( (x @ W)[j][k] )   (transposed, bf16, in d_ws)
// Kernel 2: barrier-free LDS-free fused exp + MFMA GEMM + rowsum + scale + bias.
//   Each wave owns 16 rows x 128 cols, streams K=16384 in 512 steps of 32,
//   loading MFMA fragments DIRECTLY from global (adj from HBM, yT from L2).

typedef short  short8  __attribute__((ext_vector_type(8)));
typedef float  floatx4 __attribute__((ext_vector_type(4)));

#define NN 16384
#define DD 128

__device__ __forceinline__ short f2bf(float f) {
    unsigned u = __float_as_uint(f);
    u += 0x7fff + ((u >> 16) & 1);      // RNE
    return (short)(u >> 16);
}

// ---------------- Kernel 1: yT = (x @ W)^T in bf16 ----------------
// grid 256, block 256. Block handles 64 j-rows. MFMA: A = W^T (staged LDS), B = x rows.
__global__ __launch_bounds__(256, 2) void xw_kernel(
    const float* __restrict__ x, const float* __restrict__ W, short* __restrict__ yT)
{
    __shared__ short WT[128 * 136];           // WT[k][d], padded row = 136 shorts
    const int t  = threadIdx.x;
    const int j0 = blockIdx.x * 64;

    // stage W^T as bf16 (transpose during store; one-time)
    #pragma unroll
    for (int i = 0; i < 16; ++i) {
        int f4 = t + 256 * i;                 // 0..4095 float4s of W (128x128)
        int d = f4 >> 5, c4 = f4 & 31;
        float4 v = ((const float4*)W)[f4];
        WT[(4*c4 + 0) * 136 + d] = f2bf(v.x);
        WT[(4*c4 + 1) * 136 + d] = f2bf(v.y);
        WT[(4*c4 + 2) * 136 + d] = f2bf(v.z);
        WT[(4*c4 + 3) * 136 + d] = f2bf(v.w);
    }
    __syncthreads();

    const int lane = t & 63, w = t >> 6;
    const int nl = lane & 15, q = lane >> 4;
    const int j = j0 + 16 * w + nl;           // this lane's x row (B-operand n index)
    const float* xrow = x + (size_t)j * DD + 8 * q;

    floatx4 acc[8];
    #pragma unroll
    for (int kt = 0; kt < 8; ++kt) acc[kt] = (floatx4){0.f, 0.f, 0.f, 0.f};

    #pragma unroll
    for (int dstep = 0; dstep < 4; ++dstep) {
        float4 v0 = *(const float4*)(xrow + 32 * dstep);
        float4 v1 = *(const float4*)(xrow + 32 * dstep + 4);
        short8 bf;
        bf[0] = f2bf(v0.x); bf[1] = f2bf(v0.y); bf[2] = f2bf(v0.z); bf[3] = f2bf(v0.w);
        bf[4] = f2bf(v1.x); bf[5] = f2bf(v1.y); bf[6] = f2bf(v1.z); bf[7] = f2bf(v1.w);
        #pragma unroll
        for (int kt = 0; kt < 8; ++kt) {
            short8 af = *(const short8*)(&WT[(16*kt + nl) * 136 + 32*dstep + 8*q]);
            acc[kt] = __builtin_amdgcn_mfma_f32_16x16x32_bf16(af, bf, acc[kt], 0, 0, 0);
        }
    }
    // D layout: row(m=k) = 4q + r (+16kt), col(n=j) = nl -> store transposed: yT[k][j]
    #pragma unroll
    for (int kt = 0; kt < 8; ++kt) {
        #pragma unroll
        for (int r = 0; r < 4; ++r)
            yT[(size_t)(16*kt + 4*q + r) * NN + j] = f2bf(acc[kt][r]);
    }
}

// ---------------- Kernel 2: barrier-free fused exp-GEMM ----------------
// grid 256 blocks x 256 threads; wave w owns rows [bid*64+16w, +16), all 128 cols.
// No LDS, no __syncthreads in the K-loop: MFMA fragments loaded straight from global.
__global__ __launch_bounds__(256, 1) void attn_kernel(
    const float* __restrict__ adj, const short* __restrict__ yT,
    const float* __restrict__ bias, float* __restrict__ out)
{
    const int t  = threadIdx.x;
    const int la = t & 63, w = t >> 6;
    const int m = la & 15, q = la >> 4;
    const int i0 = blockIdx.x * 64 + 16 * w;      // wave's first output row

    // A: lane reads adj[i0+m][32s + 8q .. +7]  (two float4)
    const float* aptr = adj + (size_t)(i0 + m) * NN + 8 * q;
    // B: lane reads yT[16nt+m][32s + 8q .. +7]  (one uint4 = 8 bf16)
    const short* bptr = yT + (size_t)m * NN + 8 * q;

    floatx4 acc[8];
    #pragma unroll
    for (int nt = 0; nt < 8; ++nt) acc[nt] = (floatx4){0.f, 0.f, 0.f, 0.f};
    float psumA = 0.f, psumB = 0.f;

    // 2-slot register pipeline
    float4 A00, A01, A10, A11;
    uint4  B0[8], B1[8];

    auto load_slot = [&](int s, float4& Aa, float4& Ab, uint4* B) {
        const float* ap = aptr + (size_t)s * 32;
        Aa = *(const float4*)ap;
        Ab = *(const float4*)(ap + 4);
        const short* bp = bptr + (size_t)s * 32;
        #pragma unroll
        for (int nt = 0; nt < 8; ++nt)
            B[nt] = *(const uint4*)(bp + (size_t)nt * (16 * NN));
    };
    auto step = [&](const float4& Aa, const float4& Ab, const uint4* B, float& psum) {
        float e0 = __expf(Aa.x), e1 = __expf(Aa.y), e2 = __expf(Aa.z), e3 = __expf(Aa.w);
        float e4 = __expf(Ab.x), e5 = __expf(Ab.y), e6 = __expf(Ab.z), e7 = __expf(Ab.w);
        psum += ((e0 + e1) + (e2 + e3)) + ((e4 + e5) + (e6 + e7));
        short8 af;
        af[0] = f2bf(e0); af[1] = f2bf(e1); af[2] = f2bf(e2); af[3] = f2bf(e3);
        af[4] = f2bf(e4); af[5] = f2bf(e5); af[6] = f2bf(e6); af[7] = f2bf(e7);
        #pragma unroll
        for (int nt = 0; nt < 8; ++nt) {
            short8 bf = *(const short8*)&B[nt];
            acc[nt] = __builtin_amdgcn_mfma_f32_16x16x32_bf16(af, bf, acc[nt], 0, 0, 0);
        }
    };

    load_slot(0, A00, A01, B0);
    load_slot(1, A10, A11, B1);
    #pragma unroll 1
    for (int s = 0; s < NN / 32; s += 2) {
        step(A00, A01, B0, psumA);
        if (s + 2 < NN / 32) load_slot(s + 2, A00, A01, B0);
        step(A10, A11, B1, psumB);
        if (s + 3 < NN / 32) load_slot(s + 3, A10, A11, B1);
    }

    // rowsum: lane(m,q) covered k = 8q..8q+7 (mod 32); reduce across q lanes
    float sum = psumA + psumB;
    sum += __shfl_xor(sum, 16);
    sum += __shfl_xor(sum, 32);
    float inv = 1.0f / sum;                    // valid for row m on every lane
    float invr[4];
    #pragma unroll
    for (int r = 0; r < 4; ++r) invr[r] = __shfl(inv, 4 * q + r);   // row 4q+r

    // D layout: col(n) = m, row = 4q + r
    #pragma unroll
    for (int nt = 0; nt < 8; ++nt) {
        float bv = bias[16 * nt + m];
        #pragma unroll
        for (int r = 0; r < 4; ++r)
            out[(size_t)(i0 + 4 * q + r) * DD + 16 * nt + m] = acc[nt][r] * invr[r] + bv;
    }
}

extern "C" void kernel_launch(void* const* d_in, const int* in_sizes, int n_in,
                              void* d_out, int out_size, void* d_ws, size_t ws_size,
                              hipStream_t stream)
{
    const float* x    = (const float*)d_in[0];
    const float* adj  = (const float*)d_in[1];
    const float* W    = (const float*)d_in[2];
    const float* bias = (const float*)d_in[3];
    float* out = (float*)d_out;
    short* yT  = (short*)d_ws;                 // 128 x 16384 bf16 = 4 MiB

    hipLaunchKernelGGL(xw_kernel,   dim3(256), dim3(256), 0, stream, x, W, yT);
    hipLaunchKernelGGL(attn_kernel, dim3(256), dim3(256), 0, stream, adj, yT, bias, out);
}